// Round 8
// baseline (470.901 us; speedup 1.0000x reference)
//
#include <hip/hip_runtime.h>
#include <math.h>

// ---------------------------------------------------------------------------
// GAT 4-layer forward.
// GEMMs: bf16 MFMA 2-term split (C ~ Ah*Wh + Al*Wh) -> fp32 acc; alpha dots
// fused in GEMM epilogue. h stored fp16.
// Aggregation: per-16-dst-row block mini-GEMM via MFMA f16:
//   out[16][HC] = W[16][K] x Hgather[K][HC],  W = softmax weights (fp16,
//   logit-shifted by -5), den in fp32 LDS atomics. Edges of 16 CSR rows are
//   contiguous in col[] -> chunked K loop (64 edges/chunk).
// ---------------------------------------------------------------------------

typedef __attribute__((ext_vector_type(8))) short short8;
typedef __attribute__((ext_vector_type(4))) float f32x4;
typedef _Float16 half8v __attribute__((ext_vector_type(8)));

__device__ __forceinline__ unsigned short f2bf(float f) {
  unsigned int u = __builtin_bit_cast(unsigned int, f);
  unsigned int r = u + 0x7FFFu + ((u >> 16) & 1u);   // RNE
  return (unsigned short)(r >> 16);
}
__device__ __forceinline__ float bf2f(unsigned short h) {
  unsigned int u = ((unsigned int)h) << 16;
  return __builtin_bit_cast(float, u);
}
__device__ __forceinline__ unsigned short f2h(float f) {
  _Float16 h = (_Float16)f;
  return __builtin_bit_cast(unsigned short, h);
}
__device__ __forceinline__ float h2f(unsigned short u) {
  return (float)__builtin_bit_cast(_Float16, u);
}

__device__ __forceinline__ void gload16(const unsigned short* g, unsigned short* l) {
  __builtin_amdgcn_global_load_lds(
      (const __attribute__((address_space(1))) void*)g,
      (__attribute__((address_space(3))) void*)l, 16, 0, 0);
}

// ---------------- MFMA GEMM: C[M,Nc] = A2[M,2K] @ W2t[Ncpad,2K]^T ----------
template<int H>
__global__ __launch_bounds__(256) void k_gemm_mfma(
    const unsigned short* __restrict__ A2, const unsigned short* __restrict__ Wt,
    unsigned short* __restrict__ C, const float* __restrict__ avec_s,
    const float* __restrict__ avec_d, float* __restrict__ outS,
    float* __restrict__ outD, int M, int Kb, int Nc)
{
  __shared__ unsigned short lds[16384];           // 32 KB: As | Bs, reused as C-tile
  unsigned short* As = lds;
  unsigned short* Bs = lds + 8192;
  const int tid = threadIdx.x;
  const int w = tid >> 6, l = tid & 63;
  const int row0 = blockIdx.x * 128, col0 = blockIdx.y * 128;
  const int wr = w >> 1, wc = w & 1;
  const int fr = l & 15, kg = l >> 4;
  const int xr = (fr & 7) << 4;                   // read-side XOR (bytes)
  const int sK = 2 * Kb;                          // row stride of A2 and Wt
  const int csrc = 8 * ((l & 7) ^ ((l >> 3) & 7));    // pre-swizzled src col
  const int rstage = w * 32 + (l >> 3);           // + i*8

  f32x4 acc[4][4];
  #pragma unroll
  for (int i = 0; i < 4; i++)
    #pragma unroll
    for (int j = 0; j < 4; j++) acc[i][j] = (f32x4){0.f, 0.f, 0.f, 0.f};

  for (int kp = 0; kp < sK; kp += 64) {
    #pragma unroll
    for (int i = 0; i < 4; i++) {
      int r = rstage + i * 8;
      gload16(&A2[(size_t)(row0 + r) * sK + (kp + csrc)], &As[w * 2048 + i * 512]);
      gload16(&Wt[(size_t)(col0 + r) * sK + (kp + csrc)], &Bs[w * 2048 + i * 512]);
    }
    __syncthreads();
    #pragma unroll
    for (int kk = 0; kk < 2; kk++) {
      short8 a[4], b[4];
      #pragma unroll
      for (int mi = 0; mi < 4; mi++) {
        int r = wr * 64 + mi * 16 + fr;
        int off = r * 128 + ((kk * 64 + kg * 16) ^ xr);
        a[mi] = *(const short8*)((const char*)As + off);
      }
      #pragma unroll
      for (int ni = 0; ni < 4; ni++) {
        int c = wc * 64 + ni * 16 + fr;
        int off = c * 128 + ((kk * 64 + kg * 16) ^ xr);
        b[ni] = *(const short8*)((const char*)Bs + off);
      }
      #pragma unroll
      for (int mi = 0; mi < 4; mi++)
        #pragma unroll
        for (int ni = 0; ni < 4; ni++)
          acc[mi][ni] = __builtin_amdgcn_mfma_f32_16x16x32_bf16(
              a[mi], b[ni], acc[mi][ni], 0, 0, 0);
    }
    __syncthreads();
  }

  // ---- epilogue: acc -> swizzled LDS C-tile (fp16) ----
  #pragma unroll
  for (int mi = 0; mi < 4; mi++)
    #pragma unroll
    for (int ni = 0; ni < 4; ni++)
      #pragma unroll
      for (int rr = 0; rr < 4; rr++) {
        int row = wr * 64 + mi * 16 + kg * 4 + rr;
        int c = wc * 64 + ni * 16 + fr;
        int sc = c ^ (((row >> 1) & 7) << 3);
        lds[row * 128 + sc] = f2h(acc[mi][ni][rr]);
      }
  __syncthreads();

  // ---- coalesced store + fused alpha ----
  constexpr int RW = (H == 8) ? 4 : 16;           // shfl reduce width per head
  const int Ch = Nc / H;                          // head dim
  const int rbase = tid >> 4;                     // 0..15
  const int cc = tid & 15;
  const int c0 = cc * 8;                          // block-local col chunk
  const int gc0 = col0 + c0;
  float as8[8], ad8[8];
  #pragma unroll
  for (int j = 0; j < 8; j++) {
    bool ok = (gc0 + j) < Nc;
    as8[j] = ok ? avec_s[gc0 + j] : 0.f;
    ad8[j] = ok ? avec_d[gc0 + j] : 0.f;
  }
  #pragma unroll
  for (int i = 0; i < 8; i++) {
    int row = rbase + i * 16;
    int gr = row0 + row;
    int scc = c0 ^ (((row >> 1) & 7) << 3);
    short8 cv = *(const short8*)&lds[row * 128 + scc];
    if (gr < M && gc0 < Nc)
      *(short8*)&C[(size_t)gr * Nc + gc0] = cv;
    float ps = 0.f, pd = 0.f;
    #pragma unroll
    for (int j = 0; j < 8; j++) {
      float cf = h2f((unsigned short)cv[j]);
      ps = fmaf(cf, as8[j], ps);
      pd = fmaf(cf, ad8[j], pd);
    }
    #pragma unroll
    for (int off = 1; off < RW; off <<= 1) {
      ps += __shfl_xor(ps, off);
      pd += __shfl_xor(pd, off);
    }
    if ((tid & (RW - 1)) == 0 && gr < M) {
      int head = gc0 / Ch;
      atomicAdd(&outS[gr * H + head], ps);
      atomicAdd(&outD[gr * H + head], pd);
    }
  }
}

// ---------------- pack layer-1 input: x fp32 [N,128] -> A2 [Mpad,256] ------
__global__ __launch_bounds__(256) void k_packX(const float* __restrict__ x,
    unsigned short* __restrict__ A2, int N, int Mpad)
{
  int row = blockIdx.x * 8 + (threadIdx.x >> 5);
  int c = (threadIdx.x & 31) * 4;
  if (row >= Mpad) return;
  float4 v = make_float4(0.f, 0.f, 0.f, 0.f);
  if (row < N) v = *(const float4*)&x[(size_t)row * 128 + c];
  float f[4] = {v.x, v.y, v.z, v.w};
  unsigned short hi[4], lo[4];
  #pragma unroll
  for (int i = 0; i < 4; i++) {
    hi[i] = f2bf(f[i]);
    lo[i] = f2bf(f[i] - bf2f(hi[i]));
  }
  size_t base = (size_t)row * 256 + c;
  *(uint2*)&A2[base] = make_uint2((unsigned)hi[0] | ((unsigned)hi[1] << 16),
                                  (unsigned)hi[2] | ((unsigned)hi[3] << 16));
  *(uint2*)&A2[base + 128] = make_uint2((unsigned)lo[0] | ((unsigned)lo[1] << 16),
                                        (unsigned)lo[2] | ((unsigned)lo[3] << 16));
}

// ---------------- pack W fp32 [K,NC] -> W2t bf16 [NCPAD,2K] = [Wh|Wh] ------
__global__ void k_packW(const float* __restrict__ W, unsigned short* __restrict__ Wt,
                        int K, int NC, int NCPAD)
{
  int idx = blockIdx.x * 256 + threadIdx.x;
  int K2 = 2 * K;
  if (idx >= NCPAD * K2) return;
  int c = idx / K2, kp = idx % K2;
  unsigned short o = 0;
  if (c < NC) o = f2bf(W[(size_t)(kp % K) * NC + c]);
  Wt[(size_t)c * K2 + kp] = o;
}

// ------------- MFMA aggregate: out[16 rows][HC] = W[16][K] x Hg[K][HC] -----
// Per block: 16 dst rows (CSR edges contiguous). Chunks of 64 edges:
//  phase1: thread-per-(edge,head) weight exp -> fp16 scatter into swizzled
//          A-tile Aw[H][16][64]; fp32 den via LDS atomics.
//  stage:  Hg[64][HC] fp16 via global_load_lds, chunk-XOR gk=(k>>3)&3.
//  mfma:   f32_16x16x32_f16, A-frag row=l&15 (dst), B-frag n=l&15 (ch).
template<int H, int HC, int ELU, int SPLIT>
__global__ __launch_bounds__(256) void k_agg_mfma(
    const unsigned short* __restrict__ h,
    const float* __restrict__ as, const float* __restrict__ ad,
    const int* __restrict__ rowptr, const int* __restrict__ col,
    const float* __restrict__ bias, float* __restrict__ xout,
    unsigned short* __restrict__ a2out, int N)
{
  constexpr int CK = 64;               // edges per chunk
  constexpr int NT = HC / 16;          // n-tiles
  constexpr int NTW = NT / 4;          // n-tiles per wave
  constexpr int C = HC / H;            // head dim
  constexpr int CPR = HC / 8;          // 16B chunks per h row
  constexpr int RPI = 64 / CPR;        // rows per gload instr
  constexpr int IPW = 16 / RPI;        // gload instrs per wave

  __shared__ unsigned short Hg[CK * HC];
  __shared__ unsigned short Aw[H * 16 * CK];
  __shared__ float den[16 * H];
  __shared__ int colv[CK];
  __shared__ int rp[17];

  const int tid = threadIdx.x;
  const int w = tid >> 6, l = tid & 63;
  const int r0 = blockIdx.x * 16;

  if (tid < 17) rp[tid] = rowptr[min(r0 + tid, N)];
  if (tid < 16 * H) den[tid] = 0.f;

  f32x4 acc[NTW];
  #pragma unroll
  for (int i = 0; i < NTW; i++) acc[i] = (f32x4){0.f, 0.f, 0.f, 0.f};
  __syncthreads();
  const int e0 = rp[0], e1 = rp[16];

  for (int ce = e0; ce < e1; ce += CK) {
    const int cnt = min(CK, e1 - ce);
    // ---- zero A-tile + load col chunk ----
    unsigned int* az = (unsigned int*)Aw;
    for (int i = tid; i < H * 16 * CK / 2; i += 256) az[i] = 0u;
    if (tid < CK) colv[tid] = col[min(ce + tid, e1 - 1)];
    __syncthreads();
    // ---- stage Hg (issue early; latency hides under phase 1) ----
    #pragma unroll
    for (int i = 0; i < IPW; i++) {
      int rowb = w * 16 + i * RPI;
      int row = rowb + l / CPR;
      int ck = l % CPR;
      int gk = (row >> 3) & 3;
      gload16(&h[(size_t)colv[row] * HC + (ck ^ gk) * 8], &Hg[rowb * HC]);
    }
    // ---- phase 1: weights ----
    for (int p = tid; p < cnt * H; p += 256) {
      int eo = p / H, hd = p % H;
      int e = ce + eo;
      int rl = 0;                       // max r with rp[r] <= e
      if (rp[rl + 8] <= e) rl += 8;
      if (rp[rl + 4] <= e) rl += 4;
      if (rp[rl + 2] <= e) rl += 2;
      if (rp[rl + 1] <= e) rl += 1;
      int s = colv[eo];
      float lg = as[s * H + hd] + ad[(r0 + rl) * H + hd];
      lg = fmaxf(lg, 0.2f * lg);
      float wgt = __expf(lg - 5.0f);    // shift-invariant; fp16-safe range
      wgt = (wgt < 6.2e-5f) ? 0.f : fminf(wgt, 60000.f);
      unsigned short wq = f2h(wgt);
      atomicAdd(&den[rl * H + hd], h2f(wq));
      Aw[hd * (16 * CK) + rl * CK + (((eo >> 3) ^ (rl & 7)) << 3) + (eo & 7)] = wq;
    }
    __syncthreads();                    // drains vmcnt -> Hg + Aw ready
    // ---- MFMA ----
    #pragma unroll
    for (int ks = 0; ks < CK / 32; ks++) {
      #pragma unroll
      for (int tt = 0; tt < NTW; tt++) {
        const int t = w * NTW + tt;
        const int head = (t * 16) / C;
        int rA = l & 15;
        int cA = (ks * 4 + (l >> 4)) ^ (rA & 7);
        short8 a_s = *(const short8*)&Aw[head * (16 * CK) + rA * CK + cA * 8];
        int kb = ks * 32 + (l >> 4) * 8;
        int gk = (ks * 4 + (l >> 4)) & 3;
        int ch = t * 16 + (l & 15);
        int bidx = kb * HC + (((ch >> 3) ^ gk) << 3) + (ch & 7);
        short8 b_s;
        #pragma unroll
        for (int j = 0; j < 8; j++) b_s[j] = (short)Hg[bidx + j * HC];
        acc[tt] = __builtin_amdgcn_mfma_f32_16x16x32_f16(
            __builtin_bit_cast(half8v, a_s), __builtin_bit_cast(half8v, b_s),
            acc[tt], 0, 0, 0);
      }
    }
    __syncthreads();                    // Hg/Aw free for next chunk
  }
  // ---- epilogue ----
  #pragma unroll
  for (int tt = 0; tt < NTW; tt++) {
    const int t = w * NTW + tt;
    const int ch = t * 16 + (l & 15);
    const int head = ch / C;
    #pragma unroll
    for (int rr = 0; rr < 4; rr++) {
      int rl = (l >> 4) * 4 + rr;
      int grow = r0 + rl;
      if (grow >= N) continue;
      float v = acc[tt][rr] / (den[rl * H + head] + 1e-16f) + bias[ch];
      if (ELU) v = v > 0.f ? v : expm1f(v);
      if constexpr (SPLIT) {
        unsigned short hi = f2bf(v);
        unsigned short lo = f2bf(v - bf2f(hi));
        a2out[(size_t)grow * (2 * HC) + ch] = hi;
        a2out[(size_t)grow * (2 * HC) + HC + ch] = lo;
      } else {
        xout[(size_t)grow * HC + ch] = v;
      }
    }
  }
}

// ------------------------- CSR construction --------------------------------
__global__ void k_init(int* deg, float* pool, unsigned short* A2, int N, int B,
                       int Mpad) {
  int i = blockIdx.x * 256 + threadIdx.x;
  if (i < N) deg[i] = 1;                  // self loop
  if (i < B * 64) pool[i] = 0.f;
  int padn = (Mpad - N) * 512;            // zero stride-512 pad rows of A2
  if (i < padn) A2[(size_t)N * 512 + i] = 0;
}

__global__ void k_deg(const int* __restrict__ ei, int* deg, int E) {
  int e = blockIdx.x * 256 + threadIdx.x;
  if (e < E) atomicAdd(&deg[ei[E + e]], 1);
}

// counts per graph via binary search over the SORTED batch array
__global__ void k_counts(const int* __restrict__ bat, int* cnt, int N, int B) {
  int b = threadIdx.x;
  if (b >= B) return;
  int lo0 = 0, hi0 = N;
  while (lo0 < hi0) { int mid = (lo0 + hi0) >> 1; if (bat[mid] < b) lo0 = mid + 1; else hi0 = mid; }
  int lo1 = lo0, hi1 = N;
  while (lo1 < hi1) { int mid = (lo1 + hi1) >> 1; if (bat[mid] < b + 1) lo1 = mid + 1; else hi1 = mid; }
  cnt[b] = lo1 - lo0;
}

__global__ __launch_bounds__(256) void k_scan1(const int* __restrict__ deg,
                                               int* csum, int N, int chunk) {
  int bid = blockIdx.x, t = threadIdx.x;
  int lo = bid * chunk, hi = min(lo + chunk, N);
  int s = 0;
  for (int i = lo + t; i < hi; i += 256) s += deg[i];
  #pragma unroll
  for (int off = 32; off; off >>= 1) s += __shfl_xor(s, off);
  __shared__ int sh[4];
  if ((t & 63) == 0) sh[t >> 6] = s;
  __syncthreads();
  if (t == 0) csum[bid] = sh[0] + sh[1] + sh[2] + sh[3];
}

__global__ __launch_bounds__(256) void k_scan2(const int* __restrict__ csum,
                                               int* coff) {
  __shared__ int s[256];
  int t = threadIdx.x;
  int v0 = csum[t];
  s[t] = v0;
  for (int off = 1; off < 256; off <<= 1) {
    __syncthreads();
    int v = (t >= off) ? s[t - off] : 0;
    __syncthreads();
    s[t] += v;
  }
  __syncthreads();
  coff[t] = s[t] - v0;
}

__global__ __launch_bounds__(256) void k_scan3(const int* __restrict__ deg,
    const int* __restrict__ coff, int* rowptr, int* cursor, int N, int chunk) {
  __shared__ int s[256];
  int bid = blockIdx.x, t = threadIdx.x;
  int i = bid * chunk + t;
  int v = (t < chunk && i < N) ? deg[i] : 0;
  s[t] = v;
  for (int off = 1; off < 256; off <<= 1) {
    __syncthreads();
    int x = (t >= off) ? s[t - off] : 0;
    __syncthreads();
    s[t] += x;
  }
  __syncthreads();
  int excl = s[t] - v + coff[bid];
  if (t < chunk && i < N) {
    rowptr[i] = excl;
    cursor[i] = excl;
    if (i == N - 1) rowptr[N] = excl + v;
  }
}

__global__ void k_scatter(const int* __restrict__ ei, int* cursor, int* col,
                          int E, int N) {
  int idx = blockIdx.x * 256 + threadIdx.x;
  if (idx >= E + N) return;
  int s, d;
  if (idx < E) { s = ei[idx]; d = ei[E + idx]; }
  else         { s = d = idx - E; }
  int pos = atomicAdd(&cursor[d], 1);
  col[pos] = s;
}

// ------------------------------ pooling ------------------------------------
__global__ __launch_bounds__(256) void k_pool(const float* __restrict__ xg,
    const int* __restrict__ bat, float* pool, int N) {
  int lane = threadIdx.x & 63, w = threadIdx.x >> 6;
  int base = (blockIdx.x * 4 + w) * 16;
  if (base >= N) return;
  int end = min(base + 16, N);
  float local = 0.f;
  int curb = bat[base];
  for (int n = base; n < end; n++) {
    int b = bat[n];
    if (b != curb) {
      atomicAdd(&pool[curb * 64 + lane], local);
      local = 0.f; curb = b;
    }
    local += xg[(size_t)n * 64 + lane];
  }
  atomicAdd(&pool[curb * 64 + lane], local);
}

__global__ void k_final(const float* __restrict__ pool, const int* __restrict__ cnt,
    const float* __restrict__ Wl, const float* __restrict__ bl,
    float* __restrict__ out, int B) {
  int lane = threadIdx.x;                 // 64 threads
  int c = (lane < B) ? cnt[lane] : 0;
  #pragma unroll
  for (int off = 32; off; off >>= 1) c = max(c, __shfl_xor(c, off));
  float invm = 1.f / (float)c;
  float wl = Wl[lane];
  for (int b = 0; b < B; b++) {
    float ps = pool[b * 64 + lane] * wl;
    #pragma unroll
    for (int off = 32; off; off >>= 1) ps += __shfl_xor(ps, off);
    if (lane == 0) out[b] = ps * invm + bl[0];
  }
}

// ---------------------------------------------------------------------------
extern "C" void kernel_launch(void* const* d_in, const int* in_sizes, int n_in,
                              void* d_out, int out_size, void* d_ws, size_t ws_size,
                              hipStream_t stream)
{
  (void)n_in; (void)ws_size;
  const float* x   = (const float*)d_in[0];
  const int*   ei  = (const int*)d_in[1];
  const int*   bat = (const int*)d_in[2];
  const float* W1  = (const float*)d_in[3];
  const float* as1 = (const float*)d_in[4];
  const float* ad1 = (const float*)d_in[5];
  const float* b1  = (const float*)d_in[6];
  const float* W2  = (const float*)d_in[7];
  const float* as2 = (const float*)d_in[8];
  const float* ad2 = (const float*)d_in[9];
  const float* b2  = (const float*)d_in[10];
  const float* W3  = (const float*)d_in[11];
  const float* as3 = (const float*)d_in[12];
  const float* ad3 = (const float*)d_in[13];
  const float* b3  = (const float*)d_in[14];
  const float* W4  = (const float*)d_in[15];
  const float* as4 = (const float*)d_in[16];
  const float* ad4 = (const float*)d_in[17];
  const float* b4  = (const float*)d_in[18];
  const float* Wl  = (const float*)d_in[19];
  const float* bl  = (const float*)d_in[20];
  float* out = (float*)d_out;

  const int N = in_sizes[0] / 128;
  const int E = in_sizes[1] / 2;
  const int B = out_size;
  const int Mpad = ((N + 127) / 128) * 128;

  char* p = (char*)d_ws;
  auto alloc = [&](size_t bytes) -> void* {
    void* r = (void*)p;
    p += ((bytes + 255) & ~(size_t)255);
    return r;
  };
  unsigned short* A2 = (unsigned short*)alloc((size_t)Mpad * 512 * 2);
  unsigned short* hbuf = (unsigned short*)alloc((size_t)N * 256 * 2);
  unsigned short* w2t1 = (unsigned short*)alloc((size_t)256 * 512 * 2);
  unsigned short* w2t2 = (unsigned short*)alloc((size_t)256 * 512 * 2);
  unsigned short* w2t3 = (unsigned short*)alloc((size_t)256 * 512 * 2);
  unsigned short* w2t4 = (unsigned short*)alloc((size_t)128 * 512 * 2);
  float* aAll  = (float*)alloc((size_t)N * 22 * 4);
  float* aSb   = aAll;
  float* aDb   = aAll + (size_t)N * 11;
  int*   deg   = (int*)alloc((size_t)N * 4);
  int*   rowptr= (int*)alloc((size_t)(N + 1) * 4);
  int*   cursor= (int*)alloc((size_t)N * 4);
  int*   col   = (int*)alloc((size_t)(E + N) * 4);
  int*   csum  = (int*)alloc(256 * 4);
  int*   coff  = (int*)alloc(256 * 4);
  float* pool  = (float*)alloc((size_t)B * 64 * 4);
  int*   cnt   = (int*)alloc((size_t)B * 4);
  float* xpool = (float*)A2;              // layer-4 output reuses A2 (fp32 [N,64])

  const int chunk = (N + 255) / 256;
  dim3 T(256);

  // ---- CSR build + init ----
  k_init<<<dim3((N + 255) / 256), T, 0, stream>>>(deg, pool, A2, N, B, Mpad);
  k_deg<<<dim3((E + 255) / 256), T, 0, stream>>>(ei, deg, E);
  k_counts<<<dim3(1), dim3(64), 0, stream>>>(bat, cnt, N, B);
  k_scan1<<<dim3(256), T, 0, stream>>>(deg, csum, N, chunk);
  k_scan2<<<dim3(1), T, 0, stream>>>(csum, coff);
  k_scan3<<<dim3(256), T, 0, stream>>>(deg, coff, rowptr, cursor, N, chunk);
  k_scatter<<<dim3((E + N + 255) / 256), T, 0, stream>>>(ei, cursor, col, E, N);
  hipMemsetAsync(aAll, 0, (size_t)N * 22 * 4, stream);

  // ---- weight + input packing ----
  k_packX<<<dim3(Mpad / 8), T, 0, stream>>>(x, A2, N, Mpad);
  k_packW<<<dim3((256 * 256 + 255) / 256), T, 0, stream>>>(W1, w2t1, 128, 256, 256);
  k_packW<<<dim3((256 * 512 + 255) / 256), T, 0, stream>>>(W2, w2t2, 256, 256, 256);
  k_packW<<<dim3((256 * 512 + 255) / 256), T, 0, stream>>>(W3, w2t3, 256, 256, 256);
  k_packW<<<dim3((128 * 512 + 255) / 256), T, 0, stream>>>(W4, w2t4, 256, 64, 128);

  dim3 nagg((N + 15) / 16);
  dim3 g2(Mpad / 128, 2), g1(Mpad / 128, 1);

  // per-layer alpha buffers inside the arena
  float* aS1 = aSb;                 float* aD1 = aDb;                 // N*8
  float* aS2 = aSb + (size_t)N * 8; float* aD2 = aDb + (size_t)N * 8; // N
  float* aS3 = aSb + (size_t)N * 9; float* aD3 = aDb + (size_t)N * 9; // N
  float* aS4 = aSb + (size_t)N * 10;float* aD4 = aDb + (size_t)N * 10;// N

  // ---- layer 1: [N,128]@[128,256], H=8, ELU ----
  k_gemm_mfma<8><<<g2, T, 0, stream>>>(A2, w2t1, hbuf, as1, ad1, aS1, aD1, N, 128, 256);
  k_agg_mfma<8, 256, 1, 1><<<nagg, T, 0, stream>>>(hbuf, aS1, aD1, rowptr, col, b1,
                                                   nullptr, A2, N);
  // ---- layer 2 ----
  k_gemm_mfma<1><<<g2, T, 0, stream>>>(A2, w2t2, hbuf, as2, ad2, aS2, aD2, N, 256, 256);
  k_agg_mfma<1, 256, 1, 1><<<nagg, T, 0, stream>>>(hbuf, aS2, aD2, rowptr, col, b2,
                                                   nullptr, A2, N);
  // ---- layer 3 ----
  k_gemm_mfma<1><<<g2, T, 0, stream>>>(A2, w2t3, hbuf, as3, ad3, aS3, aD3, N, 256, 256);
  k_agg_mfma<1, 256, 1, 1><<<nagg, T, 0, stream>>>(hbuf, aS3, aD3, rowptr, col, b3,
                                                   nullptr, A2, N);
  // ---- layer 4: [N,256]@[256,64], H=1, no ELU ----
  k_gemm_mfma<1><<<g1, T, 0, stream>>>(A2, w2t4, hbuf, as4, ad4, aS4, aD4, N, 256, 64);
  k_agg_mfma<1, 64, 0, 0><<<nagg, T, 0, stream>>>(hbuf, aS4, aD4, rowptr, col, b4,
                                                  xpool, nullptr, N);

  // ---- pooling + final linear ----
  k_pool<<<dim3((N + 63) / 64), T, 0, stream>>>(xpool, bat, pool, N);
  k_final<<<dim3(1), dim3(64), 0, stream>>>(pool, cnt, Wl, bl, out, B);
}

// Round 9
// 450.505 us; speedup vs baseline: 1.0453x; 1.0453x over previous
//
#include <hip/hip_runtime.h>
#include <math.h>

// ---------------------------------------------------------------------------
// GAT 4-layer forward.
// GEMMs: bf16 MFMA 2-term split (C ~ Ah*Wh + Al*Wh) -> fp32 acc; alpha dots
// fused in GEMM epilogue (LDS C-tile). h stored fp16.
// Aggregation: CSR per-dst wave; lane-parallel logit/exp phase; gather phase
// uses v_readlane (SGPR broadcast) / tiny-LDS broadcast instead of
// ds_bpermute-based __shfl (round-8 MFMA variant regressed: bank conflicts).
// ---------------------------------------------------------------------------

typedef __attribute__((ext_vector_type(8))) short short8;
typedef __attribute__((ext_vector_type(4))) float f32x4;

__device__ __forceinline__ unsigned short f2bf(float f) {
  unsigned int u = __builtin_bit_cast(unsigned int, f);
  unsigned int r = u + 0x7FFFu + ((u >> 16) & 1u);   // RNE
  return (unsigned short)(r >> 16);
}
__device__ __forceinline__ float bf2f(unsigned short h) {
  unsigned int u = ((unsigned int)h) << 16;
  return __builtin_bit_cast(float, u);
}
__device__ __forceinline__ unsigned short f2h(float f) {
  _Float16 h = (_Float16)f;
  return __builtin_bit_cast(unsigned short, h);
}
__device__ __forceinline__ float h2f(unsigned short u) {
  return (float)__builtin_bit_cast(_Float16, u);
}

__device__ __forceinline__ void gload16(const unsigned short* g, unsigned short* l) {
  __builtin_amdgcn_global_load_lds(
      (const __attribute__((address_space(1))) void*)g,
      (__attribute__((address_space(3))) void*)l, 16, 0, 0);
}

// ---------------- MFMA GEMM: C[M,Nc] = A2[M,2K] @ W2t[Ncpad,2K]^T ----------
template<int H>
__global__ __launch_bounds__(256) void k_gemm_mfma(
    const unsigned short* __restrict__ A2, const unsigned short* __restrict__ Wt,
    unsigned short* __restrict__ C, const float* __restrict__ avec_s,
    const float* __restrict__ avec_d, float* __restrict__ outS,
    float* __restrict__ outD, int M, int Kb, int Nc)
{
  __shared__ unsigned short lds[16384];           // 32 KB: As | Bs, reused as C-tile
  unsigned short* As = lds;
  unsigned short* Bs = lds + 8192;
  const int tid = threadIdx.x;
  const int w = tid >> 6, l = tid & 63;
  const int row0 = blockIdx.x * 128, col0 = blockIdx.y * 128;
  const int wr = w >> 1, wc = w & 1;
  const int fr = l & 15, kg = l >> 4;
  const int xr = (fr & 7) << 4;                   // read-side XOR (bytes)
  const int sK = 2 * Kb;                          // row stride of A2 and Wt
  const int csrc = 8 * ((l & 7) ^ ((l >> 3) & 7));    // pre-swizzled src col
  const int rstage = w * 32 + (l >> 3);           // + i*8

  f32x4 acc[4][4];
  #pragma unroll
  for (int i = 0; i < 4; i++)
    #pragma unroll
    for (int j = 0; j < 4; j++) acc[i][j] = (f32x4){0.f, 0.f, 0.f, 0.f};

  for (int kp = 0; kp < sK; kp += 64) {
    #pragma unroll
    for (int i = 0; i < 4; i++) {
      int r = rstage + i * 8;
      gload16(&A2[(size_t)(row0 + r) * sK + (kp + csrc)], &As[w * 2048 + i * 512]);
      gload16(&Wt[(size_t)(col0 + r) * sK + (kp + csrc)], &Bs[w * 2048 + i * 512]);
    }
    __syncthreads();
    #pragma unroll
    for (int kk = 0; kk < 2; kk++) {
      short8 a[4], b[4];
      #pragma unroll
      for (int mi = 0; mi < 4; mi++) {
        int r = wr * 64 + mi * 16 + fr;
        int off = r * 128 + ((kk * 64 + kg * 16) ^ xr);
        a[mi] = *(const short8*)((const char*)As + off);
      }
      #pragma unroll
      for (int ni = 0; ni < 4; ni++) {
        int c = wc * 64 + ni * 16 + fr;
        int off = c * 128 + ((kk * 64 + kg * 16) ^ xr);
        b[ni] = *(const short8*)((const char*)Bs + off);
      }
      #pragma unroll
      for (int mi = 0; mi < 4; mi++)
        #pragma unroll
        for (int ni = 0; ni < 4; ni++)
          acc[mi][ni] = __builtin_amdgcn_mfma_f32_16x16x32_bf16(
              a[mi], b[ni], acc[mi][ni], 0, 0, 0);
    }
    __syncthreads();
  }

  // ---- epilogue: acc -> swizzled LDS C-tile (fp16) ----
  #pragma unroll
  for (int mi = 0; mi < 4; mi++)
    #pragma unroll
    for (int ni = 0; ni < 4; ni++)
      #pragma unroll
      for (int rr = 0; rr < 4; rr++) {
        int row = wr * 64 + mi * 16 + kg * 4 + rr;
        int c = wc * 64 + ni * 16 + fr;
        int sc = c ^ (((row >> 1) & 7) << 3);
        lds[row * 128 + sc] = f2h(acc[mi][ni][rr]);
      }
  __syncthreads();

  // ---- coalesced store + fused alpha ----
  constexpr int RW = (H == 8) ? 4 : 16;           // shfl reduce width per head
  const int Ch = Nc / H;                          // head dim
  const int rbase = tid >> 4;                     // 0..15
  const int cc = tid & 15;
  const int c0 = cc * 8;                          // block-local col chunk
  const int gc0 = col0 + c0;
  float as8[8], ad8[8];
  #pragma unroll
  for (int j = 0; j < 8; j++) {
    bool ok = (gc0 + j) < Nc;
    as8[j] = ok ? avec_s[gc0 + j] : 0.f;
    ad8[j] = ok ? avec_d[gc0 + j] : 0.f;
  }
  #pragma unroll
  for (int i = 0; i < 8; i++) {
    int row = rbase + i * 16;
    int gr = row0 + row;
    int scc = c0 ^ (((row >> 1) & 7) << 3);
    short8 cv = *(const short8*)&lds[row * 128 + scc];
    if (gr < M && gc0 < Nc)
      *(short8*)&C[(size_t)gr * Nc + gc0] = cv;
    float ps = 0.f, pd = 0.f;
    #pragma unroll
    for (int j = 0; j < 8; j++) {
      float cf = h2f((unsigned short)cv[j]);
      ps = fmaf(cf, as8[j], ps);
      pd = fmaf(cf, ad8[j], pd);
    }
    #pragma unroll
    for (int off = 1; off < RW; off <<= 1) {
      ps += __shfl_xor(ps, off);
      pd += __shfl_xor(pd, off);
    }
    if ((tid & (RW - 1)) == 0 && gr < M) {
      int head = gc0 / Ch;
      atomicAdd(&outS[gr * H + head], ps);
      atomicAdd(&outD[gr * H + head], pd);
    }
  }
}

// ---------------- pack layer-1 input: x fp32 [N,128] -> A2 [Mpad,256] ------
__global__ __launch_bounds__(256) void k_packX(const float* __restrict__ x,
    unsigned short* __restrict__ A2, int N, int Mpad)
{
  int row = blockIdx.x * 8 + (threadIdx.x >> 5);
  int c = (threadIdx.x & 31) * 4;
  if (row >= Mpad) return;
  float4 v = make_float4(0.f, 0.f, 0.f, 0.f);
  if (row < N) v = *(const float4*)&x[(size_t)row * 128 + c];
  float f[4] = {v.x, v.y, v.z, v.w};
  unsigned short hi[4], lo[4];
  #pragma unroll
  for (int i = 0; i < 4; i++) {
    hi[i] = f2bf(f[i]);
    lo[i] = f2bf(f[i] - bf2f(hi[i]));
  }
  size_t base = (size_t)row * 256 + c;
  *(uint2*)&A2[base] = make_uint2((unsigned)hi[0] | ((unsigned)hi[1] << 16),
                                  (unsigned)hi[2] | ((unsigned)hi[3] << 16));
  *(uint2*)&A2[base + 128] = make_uint2((unsigned)lo[0] | ((unsigned)lo[1] << 16),
                                        (unsigned)lo[2] | ((unsigned)lo[3] << 16));
}

// ---------------- pack W fp32 [K,NC] -> W2t bf16 [NCPAD,2K] = [Wh|Wh] ------
__global__ void k_packW(const float* __restrict__ W, unsigned short* __restrict__ Wt,
                        int K, int NC, int NCPAD)
{
  int idx = blockIdx.x * 256 + threadIdx.x;
  int K2 = 2 * K;
  if (idx >= NCPAD * K2) return;
  int c = idx / K2, kp = idx % K2;
  unsigned short o = 0;
  if (c < NC) o = f2bf(W[(size_t)(kp % K) * NC + c]);
  Wt[(size_t)c * K2 + kp] = o;
}

// ---- segment softmax + weighted aggregate, one wave per dst row -----------
// Lane-parallel logit/exp phase; gather phase broadcasts via v_readlane
// (H=1) or a per-wave LDS table (H=8). No max shift (|logit| bounded).
// h is fp16 [N,HC]. SPLIT=1: write bf16 hi/lo into a2out (stride 2*HC).
template<int H, int HC, int ELU, int SPLIT>
__global__ __launch_bounds__(256) void k_aggregate(const unsigned short* __restrict__ h,
    const float* __restrict__ as, const float* __restrict__ ad,
    const int* __restrict__ rowptr, const int* __restrict__ col,
    const float* __restrict__ bias, float* __restrict__ xout,
    unsigned short* __restrict__ a2out, int N)
{
  constexpr int VEC = HC / 64;            // 4 (HC=256) or 1 (HC=64)
  constexpr int C = HC / H;
  constexpr int CH = (H == 8) ? 8 : 64;   // edges per chunk
  __shared__ float wlds[4][64];           // H=8: per-wave [eo][hd] weights
  int wave = threadIdx.x >> 6, lane = threadIdx.x & 63;
  int row = blockIdx.x * 4 + wave;
  if (row >= N) return;
  const int cb = lane * VEC;
  const int hdg = cb / C;                 // gather-phase head of this lane
  int s0 = rowptr[row], s1 = rowptr[row + 1];

  float adv = (H == 8) ? ad[row * 8 + (lane & 7)] : ad[row];
  float den = 0.f;
  float acc[VEC];
  #pragma unroll
  for (int v = 0; v < VEC; v++) acc[v] = 0.f;

  for (int base = s0; base < s1; base += CH) {
    int cnt = min(CH, s1 - base);
    // ---- phase 1: lane-parallel logits ----
    int eo = (H == 8) ? (lane >> 3) : lane;
    bool valid = eo < cnt;
    int s = col[valid ? (base + eo) : (s1 - 1)];
    float lg = ((H == 8) ? as[s * 8 + (lane & 7)] : as[s]) + adv;
    lg = fmaxf(lg, 0.2f * lg);            // leaky_relu
    float wgt = valid ? __expf(lg) : 0.f; // no max shift: |lg| bounded
    float d = wgt;
    if (H == 8) {                         // reduce over eo (stride-8 lanes)
      d += __shfl_xor(d, 8); d += __shfl_xor(d, 16); d += __shfl_xor(d, 32);
      wlds[wave][(lane >> 3) * 8 + (lane & 7)] = wgt;   // [eo][hd]
    } else {
      #pragma unroll
      for (int off = 1; off < 64; off <<= 1) d += __shfl_xor(d, off);
    }
    den += d;                             // H==8: lane holds den[lane&7]
    if (H == 8) {
      // order the wlds writes before cross-lane reads (same wave, no barrier)
      asm volatile("s_waitcnt lgkmcnt(0)" ::: "memory");
    }
    // ---- phase 2: gather with SGPR/LDS-broadcast weights ----
    #pragma unroll 2
    for (int j = 0; j < cnt; j++) {
      int sj = __builtin_amdgcn_readlane(s, (H == 8) ? (j * 8) : j);
      float wj;
      if constexpr (H == 8) {
        wj = wlds[wave][j * 8 + hdg];     // 8 banks, 8-lane broadcast each
      } else {
        wj = __builtin_bit_cast(float,
              __builtin_amdgcn_readlane(__builtin_bit_cast(int, wgt), j));
      }
      if constexpr (VEC == 4) {
        uint2 raw = *(const uint2*)&h[(size_t)sj * HC + cb];
        acc[0] = fmaf(wj, h2f((unsigned short)(raw.x & 0xFFFF)), acc[0]);
        acc[1] = fmaf(wj, h2f((unsigned short)(raw.x >> 16)),    acc[1]);
        acc[2] = fmaf(wj, h2f((unsigned short)(raw.y & 0xFFFF)), acc[2]);
        acc[3] = fmaf(wj, h2f((unsigned short)(raw.y >> 16)),    acc[3]);
      } else {
        acc[0] = fmaf(wj, h2f(h[(size_t)sj * HC + cb]), acc[0]);
      }
    }
  }
  if (H == 8) den = __shfl(den, hdg);     // den[h] lives at lane h (lane&7==h)
  float inv = 1.f / (den + 1e-16f);
  float o[VEC];
  #pragma unroll
  for (int v = 0; v < VEC; v++) {
    float t = acc[v] * inv + bias[cb + v];
    if (ELU) t = t > 0.f ? t : expm1f(t);
    o[v] = t;
  }
  if constexpr (SPLIT) {
    unsigned short hi[4], lo[4];
    #pragma unroll
    for (int v = 0; v < 4; v++) {
      hi[v] = f2bf(o[v]);
      lo[v] = f2bf(o[v] - bf2f(hi[v]));
    }
    size_t base = (size_t)row * (2 * HC) + cb;
    *(uint2*)&a2out[base] = make_uint2((unsigned)hi[0] | ((unsigned)hi[1] << 16),
                                       (unsigned)hi[2] | ((unsigned)hi[3] << 16));
    *(uint2*)&a2out[base + HC] = make_uint2((unsigned)lo[0] | ((unsigned)lo[1] << 16),
                                            (unsigned)lo[2] | ((unsigned)lo[3] << 16));
  } else if constexpr (VEC == 4) {
    *(float4*)&xout[(size_t)row * HC + cb] = make_float4(o[0], o[1], o[2], o[3]);
  } else {
    xout[(size_t)row * HC + cb] = o[0];
  }
}

// ------------------------- CSR construction --------------------------------
__global__ void k_init(int* deg, float* pool, unsigned short* A2, int N, int B,
                       int Mpad) {
  int i = blockIdx.x * 256 + threadIdx.x;
  if (i < N) deg[i] = 1;                  // self loop
  if (i < B * 64) pool[i] = 0.f;
  int padn = (Mpad - N) * 512;            // zero stride-512 pad rows of A2
  if (i < padn) A2[(size_t)N * 512 + i] = 0;
}

__global__ void k_deg(const int* __restrict__ ei, int* deg, int E) {
  int e = blockIdx.x * 256 + threadIdx.x;
  if (e < E) atomicAdd(&deg[ei[E + e]], 1);
}

// counts per graph via binary search over the SORTED batch array
__global__ void k_counts(const int* __restrict__ bat, int* cnt, int N, int B) {
  int b = threadIdx.x;
  if (b >= B) return;
  int lo0 = 0, hi0 = N;
  while (lo0 < hi0) { int mid = (lo0 + hi0) >> 1; if (bat[mid] < b) lo0 = mid + 1; else hi0 = mid; }
  int lo1 = lo0, hi1 = N;
  while (lo1 < hi1) { int mid = (lo1 + hi1) >> 1; if (bat[mid] < b + 1) lo1 = mid + 1; else hi1 = mid; }
  cnt[b] = lo1 - lo0;
}

__global__ __launch_bounds__(256) void k_scan1(const int* __restrict__ deg,
                                               int* csum, int N, int chunk) {
  int bid = blockIdx.x, t = threadIdx.x;
  int lo = bid * chunk, hi = min(lo + chunk, N);
  int s = 0;
  for (int i = lo + t; i < hi; i += 256) s += deg[i];
  #pragma unroll
  for (int off = 32; off; off >>= 1) s += __shfl_xor(s, off);
  __shared__ int sh[4];
  if ((t & 63) == 0) sh[t >> 6] = s;
  __syncthreads();
  if (t == 0) csum[bid] = sh[0] + sh[1] + sh[2] + sh[3];
}

__global__ __launch_bounds__(256) void k_scan2(const int* __restrict__ csum,
                                               int* coff) {
  __shared__ int s[256];
  int t = threadIdx.x;
  int v0 = csum[t];
  s[t] = v0;
  for (int off = 1; off < 256; off <<= 1) {
    __syncthreads();
    int v = (t >= off) ? s[t - off] : 0;
    __syncthreads();
    s[t] += v;
  }
  __syncthreads();
  coff[t] = s[t] - v0;
}

__global__ __launch_bounds__(256) void k_scan3(const int* __restrict__ deg,
    const int* __restrict__ coff, int* rowptr, int* cursor, int N, int chunk) {
  __shared__ int s[256];
  int bid = blockIdx.x, t = threadIdx.x;
  int i = bid * chunk + t;
  int v = (t < chunk && i < N) ? deg[i] : 0;
  s[t] = v;
  for (int off = 1; off < 256; off <<= 1) {
    __syncthreads();
    int x = (t >= off) ? s[t - off] : 0;
    __syncthreads();
    s[t] += x;
  }
  __syncthreads();
  int excl = s[t] - v + coff[bid];
  if (t < chunk && i < N) {
    rowptr[i] = excl;
    cursor[i] = excl;
    if (i == N - 1) rowptr[N] = excl + v;
  }
}

__global__ void k_scatter(const int* __restrict__ ei, int* cursor, int* col,
                          int E, int N) {
  int idx = blockIdx.x * 256 + threadIdx.x;
  if (idx >= E + N) return;
  int s, d;
  if (idx < E) { s = ei[idx]; d = ei[E + idx]; }
  else         { s = d = idx - E; }
  int pos = atomicAdd(&cursor[d], 1);
  col[pos] = s;
}

// ------------------------------ pooling ------------------------------------
__global__ __launch_bounds__(256) void k_pool(const float* __restrict__ xg,
    const int* __restrict__ bat, float* pool, int N) {
  int lane = threadIdx.x & 63, w = threadIdx.x >> 6;
  int base = (blockIdx.x * 4 + w) * 16;
  if (base >= N) return;
  int end = min(base + 16, N);
  float local = 0.f;
  int curb = bat[base];
  for (int n = base; n < end; n++) {
    int b = bat[n];
    if (b != curb) {
      atomicAdd(&pool[curb * 64 + lane], local);
      local = 0.f; curb = b;
    }
    local += xg[(size_t)n * 64 + lane];
  }
  atomicAdd(&pool[curb * 64 + lane], local);
}

__global__ void k_final(const float* __restrict__ pool, const int* __restrict__ cnt,
    const float* __restrict__ Wl, const float* __restrict__ bl,
    float* __restrict__ out, int B) {
  int lane = threadIdx.x;                 // 64 threads
  int c = (lane < B) ? cnt[lane] : 0;
  #pragma unroll
  for (int off = 32; off; off >>= 1) c = max(c, __shfl_xor(c, off));
  float invm = 1.f / (float)c;
  float wl = Wl[lane];
  for (int b = 0; b < B; b++) {
    float ps = pool[b * 64 + lane] * wl;
    #pragma unroll
    for (int off = 32; off; off >>= 1) ps += __shfl_xor(ps, off);
    if (lane == 0) out[b] = ps * invm + bl[0];
  }
}

// ---------------------------------------------------------------------------
extern "C" void kernel_launch(void* const* d_in, const int* in_sizes, int n_in,
                              void* d_out, int out_size, void* d_ws, size_t ws_size,
                              hipStream_t stream)
{
  (void)n_in; (void)ws_size;
  const float* x   = (const float*)d_in[0];
  const int*   ei  = (const int*)d_in[1];
  const int*   bat = (const int*)d_in[2];
  const float* W1  = (const float*)d_in[3];
  const float* as1 = (const float*)d_in[4];
  const float* ad1 = (const float*)d_in[5];
  const float* b1  = (const float*)d_in[6];
  const float* W2  = (const float*)d_in[7];
  const float* as2 = (const float*)d_in[8];
  const float* ad2 = (const float*)d_in[9];
  const float* b2  = (const float*)d_in[10];
  const float* W3  = (const float*)d_in[11];
  const float* as3 = (const float*)d_in[12];
  const float* ad3 = (const float*)d_in[13];
  const float* b3  = (const float*)d_in[14];
  const float* W4  = (const float*)d_in[15];
  const float* as4 = (const float*)d_in[16];
  const float* ad4 = (const float*)d_in[17];
  const float* b4  = (const float*)d_in[18];
  const float* Wl  = (const float*)d_in[19];
  const float* bl  = (const float*)d_in[20];
  float* out = (float*)d_out;

  const int N = in_sizes[0] / 128;
  const int E = in_sizes[1] / 2;
  const int B = out_size;
  const int Mpad = ((N + 127) / 128) * 128;

  char* p = (char*)d_ws;
  auto alloc = [&](size_t bytes) -> void* {
    void* r = (void*)p;
    p += ((bytes + 255) & ~(size_t)255);
    return r;
  };
  unsigned short* A2 = (unsigned short*)alloc((size_t)Mpad * 512 * 2);
  unsigned short* hbuf = (unsigned short*)alloc((size_t)N * 256 * 2);
  unsigned short* w2t1 = (unsigned short*)alloc((size_t)256 * 512 * 2);
  unsigned short* w2t2 = (unsigned short*)alloc((size_t)256 * 512 * 2);
  unsigned short* w2t3 = (unsigned short*)alloc((size_t)256 * 512 * 2);
  unsigned short* w2t4 = (unsigned short*)alloc((size_t)128 * 512 * 2);
  float* aAll  = (float*)alloc((size_t)N * 22 * 4);
  float* aSb   = aAll;
  float* aDb   = aAll + (size_t)N * 11;
  int*   deg   = (int*)alloc((size_t)N * 4);
  int*   rowptr= (int*)alloc((size_t)(N + 1) * 4);
  int*   cursor= (int*)alloc((size_t)N * 4);
  int*   col   = (int*)alloc((size_t)(E + N) * 4);
  int*   csum  = (int*)alloc(256 * 4);
  int*   coff  = (int*)alloc(256 * 4);
  float* pool  = (float*)alloc((size_t)B * 64 * 4);
  int*   cnt   = (int*)alloc((size_t)B * 4);
  float* xpool = (float*)A2;              // layer-4 output reuses A2 (fp32 [N,64])

  const int chunk = (N + 255) / 256;
  dim3 T(256);

  // ---- CSR build + init ----
  k_init<<<dim3((N + 255) / 256), T, 0, stream>>>(deg, pool, A2, N, B, Mpad);
  k_deg<<<dim3((E + 255) / 256), T, 0, stream>>>(ei, deg, E);
  k_counts<<<dim3(1), dim3(64), 0, stream>>>(bat, cnt, N, B);
  k_scan1<<<dim3(256), T, 0, stream>>>(deg, csum, N, chunk);
  k_scan2<<<dim3(1), T, 0, stream>>>(csum, coff);
  k_scan3<<<dim3(256), T, 0, stream>>>(deg, coff, rowptr, cursor, N, chunk);
  k_scatter<<<dim3((E + N + 255) / 256), T, 0, stream>>>(ei, cursor, col, E, N);
  hipMemsetAsync(aAll, 0, (size_t)N * 22 * 4, stream);

  // ---- weight + input packing ----
  k_packX<<<dim3(Mpad / 8), T, 0, stream>>>(x, A2, N, Mpad);
  k_packW<<<dim3((256 * 256 + 255) / 256), T, 0, stream>>>(W1, w2t1, 128, 256, 256);
  k_packW<<<dim3((256 * 512 + 255) / 256), T, 0, stream>>>(W2, w2t2, 256, 256, 256);
  k_packW<<<dim3((256 * 512 + 255) / 256), T, 0, stream>>>(W3, w2t3, 256, 256, 256);
  k_packW<<<dim3((128 * 512 + 255) / 256), T, 0, stream>>>(W4, w2t4, 256, 64, 128);

  dim3 nwav((N + 3) / 4);
  dim3 g2(Mpad / 128, 2), g1(Mpad / 128, 1);

  // per-layer alpha buffers inside the arena
  float* aS1 = aSb;                 float* aD1 = aDb;                 // N*8
  float* aS2 = aSb + (size_t)N * 8; float* aD2 = aDb + (size_t)N * 8; // N
  float* aS3 = aSb + (size_t)N * 9; float* aD3 = aDb + (size_t)N * 9; // N
  float* aS4 = aSb + (size_t)N * 10;float* aD4 = aDb + (size_t)N * 10;// N

  // ---- layer 1: [N,128]@[128,256], H=8, ELU ----
  k_gemm_mfma<8><<<g2, T, 0, stream>>>(A2, w2t1, hbuf, as1, ad1, aS1, aD1, N, 128, 256);
  k_aggregate<8, 256, 1, 1><<<nwav, T, 0, stream>>>(hbuf, aS1, aD1, rowptr, col, b1,
                                                    nullptr, A2, N);
  // ---- layer 2 ----
  k_gemm_mfma<1><<<g2, T, 0, stream>>>(A2, w2t2, hbuf, as2, ad2, aS2, aD2, N, 256, 256);
  k_aggregate<1, 256, 1, 1><<<nwav, T, 0, stream>>>(hbuf, aS2, aD2, rowptr, col, b2,
                                                    nullptr, A2, N);
  // ---- layer 3 ----
  k_gemm_mfma<1><<<g2, T, 0, stream>>>(A2, w2t3, hbuf, as3, ad3, aS3, aD3, N, 256, 256);
  k_aggregate<1, 256, 1, 1><<<nwav, T, 0, stream>>>(hbuf, aS3, aD3, rowptr, col, b3,
                                                    nullptr, A2, N);
  // ---- layer 4: [N,256]@[256,64], H=1, no ELU ----
  k_gemm_mfma<1><<<g1, T, 0, stream>>>(A2, w2t4, hbuf, as4, ad4, aS4, aD4, N, 256, 64);
  k_aggregate<1, 64, 0, 0><<<nwav, T, 0, stream>>>(hbuf, aS4, aD4, rowptr, col, b4,
                                                   xpool, nullptr, N);

  // ---- pooling + final linear ----
  k_pool<<<dim3((N + 63) / 64), T, 0, stream>>>(xpool, bat, pool, N);
  k_final<<<dim3(1), dim3(64), 0, stream>>>(pool, cnt, Wl, bl, out, B);
}